// Round 4
// baseline (174.880 us; speedup 1.0000x reference)
//
#include <hip/hip_runtime.h>

// StabilizedButterflyLayer: B=4096 rows, N=4096 cols, 12 butterfly stages.
// fp32 in / fp32 out. Single-pass fused kernel: one block = 512 threads
// processes 8 rows; each thread holds 8 fp32 elements; stages applied in
// groups of 3 under four layouts (A: contig-8, B: stride-8, C: stride-64,
// D: stride-512) with 3 XOR-swizzled LDS exchanges (3 x 16KB images).
//
// R2 lesson: cs[48]/z[8] arrays passed by pointer into group3() defeated
// SROA -> scratch spills (VGPR_Count=64, +19MB WRITE / +13MB FETCH of spill
// traffic, 63us latency-bound). Fully scalarized now. R3 lesson: the
// nontemporal builtins need a true clang ext_vector_type, not HIP's
// float4 struct.

#define BLOCK 512
#define NROWS 8
#define NCOL  4096

typedef float floatx4 __attribute__((ext_vector_type(4)));

// theta -> packed {hi16: bf16(sin), lo16: bf16(cos-1)}; |theta| <~ 0.17 so a
// 2-term poly is exact to ~1e-5. bf16 quantization of the pair costs ~2e-4
// per stage absolute; threshold is 0.109 absolute (we measured 0.031, which
// is the harness's own bf16 reference quantization).
__device__ __forceinline__ unsigned int pack_cs(float th) {
  float t2  = th * th;
  float s   = th * fmaf(t2, fmaf(t2, 8.3333333e-3f, -1.6666667e-1f), 1.0f);
  float cm1 = t2 * fmaf(t2, 4.1666667e-2f, -0.5f);
  unsigned int uc = __float_as_uint(cm1);
  uc = (uc + 0x7fffu + ((uc >> 16) & 1u)) >> 16;
  unsigned int us = __float_as_uint(s);
  us = (us + 0x7fffu + ((us >> 16) & 1u)) & 0xffff0000u;
  return us | uc;
}

// Givens rotation with c = 1 + cm1:  a' = c*a - s*b ; b' = s*a + c*b
#define ROT(a, b, cc) do {                                   \
    float cm1_ = __uint_as_float((cc) << 16);                \
    float s_   = __uint_as_float((cc) & 0xffff0000u);        \
    float y0_  = fmaf(cm1_, (a), fmaf(-s_, (b), (a)));       \
    float y1_  = fmaf(cm1_, (b), fmaf( s_, (a), (b)));       \
    (a) = y0_; (b) = y1_;                                    \
  } while (0)

// 3 stages of one group on z0..z7 (slot maps verified in R2: sub0 pairs
// (2a,2a+1)->angle slot a; sub1 pairs (i,i+2) i in {0,1,4,5} -> slots 0..3;
// sub2 pairs (i,i+4) -> slot i).
#define GROUP3(c0,c1,c2,c3,c4,c5,c6,c7,c8,c9,c10,c11) do {   \
    ROT(z0, z1, c0);  ROT(z2, z3, c1);                       \
    ROT(z4, z5, c2);  ROT(z6, z7, c3);                       \
    ROT(z0, z2, c4);  ROT(z1, z3, c5);                       \
    ROT(z4, z6, c6);  ROT(z5, z7, c7);                       \
    ROT(z0, z4, c8);  ROT(z1, z5, c9);                       \
    ROT(z2, z6, c10); ROT(z3, z7, c11);                      \
  } while (0)

__global__ __launch_bounds__(BLOCK, 4) void butterfly12_kernel(
    const float* __restrict__ xin,
    const float* __restrict__ ang,   // [12][2048] fp32
    float* __restrict__ xout) {
  __shared__ float lds[3 * NCOL];  // im1 @0 (sw1), im2 @4096 (sw1), im3 @8192 (natural)

  const int t = threadIdx.x;
  const int q = t >> 3, r = t & 7;   // B-layout: elem = 64q + r + 8k
  const int w = t >> 6, l = t & 63;  // C-layout: elem = 512w + l + 64k

  // ---------- per-thread (cos-1, sin) preload: 48 packed scalar regs ----------
  // Group A (stages 0-2): contiguous angles 4t..4t+3 per stage.
  const floatx4 aA0 = *(const floatx4*)(ang + 0 * 2048 + 4 * t);
  const floatx4 aA1 = *(const floatx4*)(ang + 1 * 2048 + 4 * t);
  const floatx4 aA2 = *(const floatx4*)(ang + 2 * 2048 + 4 * t);
  const unsigned int k0  = pack_cs(aA0.x), k1  = pack_cs(aA0.y),
                     k2  = pack_cs(aA0.z), k3  = pack_cs(aA0.w);
  const unsigned int k4  = pack_cs(aA1.x), k5  = pack_cs(aA1.y),
                     k6  = pack_cs(aA1.z), k7  = pack_cs(aA1.w);
  const unsigned int k8  = pack_cs(aA2.x), k9  = pack_cs(aA2.y),
                     k10 = pack_cs(aA2.z), k11 = pack_cs(aA2.w);
  // Group B (stages 3-5): base 32q+r, stride 8.
  const float* pB0 = ang + 3 * 2048 + 32 * q + r;
  const float* pB1 = pB0 + 2048;
  const float* pB2 = pB1 + 2048;
  const unsigned int k12 = pack_cs(pB0[0]),  k13 = pack_cs(pB0[8]),
                     k14 = pack_cs(pB0[16]), k15 = pack_cs(pB0[24]);
  const unsigned int k16 = pack_cs(pB1[0]),  k17 = pack_cs(pB1[8]),
                     k18 = pack_cs(pB1[16]), k19 = pack_cs(pB1[24]);
  const unsigned int k20 = pack_cs(pB2[0]),  k21 = pack_cs(pB2[8]),
                     k22 = pack_cs(pB2[16]), k23 = pack_cs(pB2[24]);
  // Group C (stages 6-8): base 256w+l, stride 64.
  const float* pC0 = ang + 6 * 2048 + 256 * w + l;
  const float* pC1 = pC0 + 2048;
  const float* pC2 = pC1 + 2048;
  const unsigned int k24 = pack_cs(pC0[0]),   k25 = pack_cs(pC0[64]),
                     k26 = pack_cs(pC0[128]), k27 = pack_cs(pC0[192]);
  const unsigned int k28 = pack_cs(pC1[0]),   k29 = pack_cs(pC1[64]),
                     k30 = pack_cs(pC1[128]), k31 = pack_cs(pC1[192]);
  const unsigned int k32 = pack_cs(pC2[0]),   k33 = pack_cs(pC2[64]),
                     k34 = pack_cs(pC2[128]), k35 = pack_cs(pC2[192]);
  // Group D (stages 9-11): base t, stride 512.
  const float* pD0 = ang + 9 * 2048 + t;
  const float* pD1 = pD0 + 2048;
  const float* pD2 = pD1 + 2048;
  const unsigned int k36 = pack_cs(pD0[0]),    k37 = pack_cs(pD0[512]),
                     k38 = pack_cs(pD0[1024]), k39 = pack_cs(pD0[1536]);
  const unsigned int k40 = pack_cs(pD1[0]),    k41 = pack_cs(pD1[512]),
                     k42 = pack_cs(pD1[1024]), k43 = pack_cs(pD1[1536]);
  const unsigned int k44 = pack_cs(pD2[0]),    k45 = pack_cs(pD2[512]),
                     k46 = pack_cs(pD2[1024]), k47 = pack_cs(pD2[1536]);

  // ---------- LDS addresses (float indices), all scalar ----------
  // sw1 (im1, im2): 4-float chunk c stored at chunk c ^ ((c>>4)&7);
  // verified conflict-free (<=2 lanes/bank) for every access set in R2.
  const int x  = (q >> 1) & 3;
  const int rr = r ^ ((q & 1) << 2);
  const int a0 = ((2 * t) ^ (q & 7)) << 2;      // sw1(elem 8t)   A-write f4 #0
  const int a1 = ((2 * t + 1) ^ (q & 7)) << 2;  // sw1(elem 8t+4) A-write f4 #1
  const int vB0 = 64 * q + rr + 8 * (0 ^ x);    // im1 B-read sw1(64q+r+8k); +32 -> k+4
  const int vB1 = 64 * q + rr + 8 * (1 ^ x);
  const int vB2 = 64 * q + rr + 8 * (2 ^ x);
  const int vB3 = 64 * q + rr + 8 * (3 ^ x);
  const int uB0 = vB0 + 4096, uB1 = vB1 + 4096; // im2 B-write (same swizzle)
  const int uB2 = vB2 + 4096, uB3 = vB3 + 4096;
  const int vC0 = 4096 + 512 * w + 64 * 0 + (l ^ (0 << 2));  // im2 C-read
  const int vC1 = 4096 + 512 * w + 64 * 1 + (l ^ (1 << 2));
  const int vC2 = 4096 + 512 * w + 64 * 2 + (l ^ (2 << 2));
  const int vC3 = 4096 + 512 * w + 64 * 3 + (l ^ (3 << 2));
  const int vC4 = 4096 + 512 * w + 64 * 4 + (l ^ (4 << 2));
  const int vC5 = 4096 + 512 * w + 64 * 5 + (l ^ (5 << 2));
  const int vC6 = 4096 + 512 * w + 64 * 6 + (l ^ (6 << 2));
  const int vC7 = 4096 + 512 * w + 64 * 7 + (l ^ (7 << 2));
  const int vCw = 8192 + 512 * w + l;           // im3 C-write, natural
  const int vD  = 8192 + t;                     // im3 D-read,  natural

  // ---------- row loop ----------
  const long long row0 = (long long)blockIdx.x * NROWS;
  const float* xbase = xin + row0 * NCOL + 8 * t;
  floatx4 rawA = __builtin_nontemporal_load((const floatx4*)xbase);
  floatx4 rawB = __builtin_nontemporal_load((const floatx4*)(xbase + 4));

  for (int rI = 0; rI < NROWS; ++rI) {
    float z0 = rawA.x, z1 = rawA.y, z2 = rawA.z, z3 = rawA.w;
    float z4 = rawB.x, z5 = rawB.y, z6 = rawB.z, z7 = rawB.w;
    if (rI + 1 < NROWS) {                       // prefetch next row (nontemporal)
      const float* nbase = xbase + (long long)(rI + 1) * NCOL;
      rawA = __builtin_nontemporal_load((const floatx4*)nbase);
      rawB = __builtin_nontemporal_load((const floatx4*)(nbase + 4));
    }

    GROUP3(k0, k1, k2, k3, k4, k5, k6, k7, k8, k9, k10, k11);   // stages 0-2

    floatx4 w0; w0.x = z0; w0.y = z1; w0.z = z2; w0.w = z3;     // A-write im1
    floatx4 w1; w1.x = z4; w1.y = z5; w1.z = z6; w1.w = z7;
    *(floatx4*)(lds + a0) = w0;
    *(floatx4*)(lds + a1) = w1;
    __syncthreads();

    z0 = lds[vB0]; z4 = lds[vB0 + 32];                          // B-read im1
    z1 = lds[vB1]; z5 = lds[vB1 + 32];
    z2 = lds[vB2]; z6 = lds[vB2 + 32];
    z3 = lds[vB3]; z7 = lds[vB3 + 32];
    GROUP3(k12, k13, k14, k15, k16, k17, k18, k19, k20, k21, k22, k23); // 3-5
    lds[uB0] = z0; lds[uB0 + 32] = z4;                          // B-write im2
    lds[uB1] = z1; lds[uB1 + 32] = z5;
    lds[uB2] = z2; lds[uB2 + 32] = z6;
    lds[uB3] = z3; lds[uB3 + 32] = z7;
    __syncthreads();

    z0 = lds[vC0]; z1 = lds[vC1]; z2 = lds[vC2]; z3 = lds[vC3]; // C-read im2
    z4 = lds[vC4]; z5 = lds[vC5]; z6 = lds[vC6]; z7 = lds[vC7];
    GROUP3(k24, k25, k26, k27, k28, k29, k30, k31, k32, k33, k34, k35); // 6-8
    lds[vCw + 64 * 0] = z0; lds[vCw + 64 * 1] = z1;             // C-write im3
    lds[vCw + 64 * 2] = z2; lds[vCw + 64 * 3] = z3;
    lds[vCw + 64 * 4] = z4; lds[vCw + 64 * 5] = z5;
    lds[vCw + 64 * 6] = z6; lds[vCw + 64 * 7] = z7;
    __syncthreads();

    z0 = lds[vD + 512 * 0]; z1 = lds[vD + 512 * 1];             // D-read im3
    z2 = lds[vD + 512 * 2]; z3 = lds[vD + 512 * 3];
    z4 = lds[vD + 512 * 4]; z5 = lds[vD + 512 * 5];
    z6 = lds[vD + 512 * 6]; z7 = lds[vD + 512 * 7];
    GROUP3(k36, k37, k38, k39, k40, k41, k42, k43, k44, k45, k46, k47); // 9-11

    float* orow = xout + (row0 + rI) * NCOL;                    // coalesced out
    __builtin_nontemporal_store(z0, orow + t + 512 * 0);
    __builtin_nontemporal_store(z1, orow + t + 512 * 1);
    __builtin_nontemporal_store(z2, orow + t + 512 * 2);
    __builtin_nontemporal_store(z3, orow + t + 512 * 3);
    __builtin_nontemporal_store(z4, orow + t + 512 * 4);
    __builtin_nontemporal_store(z5, orow + t + 512 * 5);
    __builtin_nontemporal_store(z6, orow + t + 512 * 6);
    __builtin_nontemporal_store(z7, orow + t + 512 * 7);
    // No extra barrier: row rI+1's im1 writes are ordered after row rI's
    // barrier #2 (im1 reads done); im2 writes after barrier #3; im3 writes
    // after rI+1's barrier #2 which is > all of rI's im3 reads.
  }
}

extern "C" void kernel_launch(void* const* d_in, const int* in_sizes, int n_in,
                              void* d_out, int out_size, void* d_ws, size_t ws_size,
                              hipStream_t stream) {
  const float* x   = (const float*)d_in[0];   // fp32 [4096][4096]
  const float* ang = (const float*)d_in[1];   // fp32 [12][2048]
  float* out = (float*)d_out;                 // fp32 [4096][4096]
  butterfly12_kernel<<<dim3(4096 / NROWS), dim3(BLOCK), 0, stream>>>(x, ang, out);
}

// Round 5
// 126.601 us; speedup vs baseline: 1.3813x; 1.3813x over previous
//
#include <hip/hip_runtime.h>

// StabilizedButterflyLayer: B=4096 rows, N=4096 cols, 12 butterfly stages.
// fp32 in / fp32 out. Single-pass fused kernel: one block = 512 threads
// processes 8 rows; each thread holds 8 fp32 elements; stages applied in
// groups of 3 under four layouts (A: contig-8, B: stride-8, C: stride-64,
// D: stride-512) with 3 XOR-swizzled LDS exchanges (3 x 16KB images).
//
// R4 lesson: __launch_bounds__(512, 4) acts as min-4-BLOCKS/CU (CUDA
// semantics) -> 8 waves/SIMD -> 64-VGPR cap -> forced spills (VGPR_Count=64,
// WRITE +28MB scratch). (512, 2) gives a 128-reg cap under that reading
// (256 under waves/EU reading) -- fits the ~100-reg working set either way.
// R3 lesson: nontemporal builtins need clang ext_vector_type, not float4.
// R2 lesson: keep everything scalarized, no address-taken locals.

#define BLOCK 512
#define NROWS 8
#define NCOL  4096

typedef float floatx4 __attribute__((ext_vector_type(4)));

// theta -> packed {hi16: bf16(sin), lo16: bf16(cos-1)}; |theta| <~ 0.17 so a
// 2-term poly is exact to ~1e-5. bf16 quantization of the pair costs ~2e-4
// per stage absolute; threshold is 0.109 absolute (measured absmax 0.031 is
// the harness's own bf16 reference quantization floor).
__device__ __forceinline__ unsigned int pack_cs(float th) {
  float t2  = th * th;
  float s   = th * fmaf(t2, fmaf(t2, 8.3333333e-3f, -1.6666667e-1f), 1.0f);
  float cm1 = t2 * fmaf(t2, 4.1666667e-2f, -0.5f);
  unsigned int uc = __float_as_uint(cm1);
  uc = (uc + 0x7fffu + ((uc >> 16) & 1u)) >> 16;
  unsigned int us = __float_as_uint(s);
  us = (us + 0x7fffu + ((us >> 16) & 1u)) & 0xffff0000u;
  return us | uc;
}

// Givens rotation with c = 1 + cm1:  a' = c*a - s*b ; b' = s*a + c*b
#define ROT(a, b, cc) do {                                   \
    float cm1_ = __uint_as_float((cc) << 16);                \
    float s_   = __uint_as_float((cc) & 0xffff0000u);        \
    float y0_  = fmaf(cm1_, (a), fmaf(-s_, (b), (a)));       \
    float y1_  = fmaf(cm1_, (b), fmaf( s_, (a), (b)));       \
    (a) = y0_; (b) = y1_;                                    \
  } while (0)

// 3 stages of one group on z0..z7 (slot maps verified in R2: sub0 pairs
// (2a,2a+1)->angle slot a; sub1 pairs (i,i+2) i in {0,1,4,5} -> slots 0..3;
// sub2 pairs (i,i+4) -> slot i).
#define GROUP3(c0,c1,c2,c3,c4,c5,c6,c7,c8,c9,c10,c11) do {   \
    ROT(z0, z1, c0);  ROT(z2, z3, c1);                       \
    ROT(z4, z5, c2);  ROT(z6, z7, c3);                       \
    ROT(z0, z2, c4);  ROT(z1, z3, c5);                       \
    ROT(z4, z6, c6);  ROT(z5, z7, c7);                       \
    ROT(z0, z4, c8);  ROT(z1, z5, c9);                       \
    ROT(z2, z6, c10); ROT(z3, z7, c11);                      \
  } while (0)

__global__ __launch_bounds__(BLOCK, 2) void butterfly12_kernel(
    const float* __restrict__ xin,
    const float* __restrict__ ang,   // [12][2048] fp32
    float* __restrict__ xout) {
  __shared__ float lds[3 * NCOL];  // im1 @0 (sw1), im2 @4096 (sw1), im3 @8192 (natural)

  const int t = threadIdx.x;
  const int q = t >> 3, r = t & 7;   // B-layout: elem = 64q + r + 8k
  const int w = t >> 6, l = t & 63;  // C-layout: elem = 512w + l + 64k

  // ---------- per-thread (cos-1, sin) preload: 48 packed scalar regs ----------
  // Group A (stages 0-2): contiguous angles 4t..4t+3 per stage.
  const floatx4 aA0 = *(const floatx4*)(ang + 0 * 2048 + 4 * t);
  const floatx4 aA1 = *(const floatx4*)(ang + 1 * 2048 + 4 * t);
  const floatx4 aA2 = *(const floatx4*)(ang + 2 * 2048 + 4 * t);
  const unsigned int k0  = pack_cs(aA0.x), k1  = pack_cs(aA0.y),
                     k2  = pack_cs(aA0.z), k3  = pack_cs(aA0.w);
  const unsigned int k4  = pack_cs(aA1.x), k5  = pack_cs(aA1.y),
                     k6  = pack_cs(aA1.z), k7  = pack_cs(aA1.w);
  const unsigned int k8  = pack_cs(aA2.x), k9  = pack_cs(aA2.y),
                     k10 = pack_cs(aA2.z), k11 = pack_cs(aA2.w);
  // Group B (stages 3-5): base 32q+r, stride 8.
  const float* pB0 = ang + 3 * 2048 + 32 * q + r;
  const float* pB1 = pB0 + 2048;
  const float* pB2 = pB1 + 2048;
  const unsigned int k12 = pack_cs(pB0[0]),  k13 = pack_cs(pB0[8]),
                     k14 = pack_cs(pB0[16]), k15 = pack_cs(pB0[24]);
  const unsigned int k16 = pack_cs(pB1[0]),  k17 = pack_cs(pB1[8]),
                     k18 = pack_cs(pB1[16]), k19 = pack_cs(pB1[24]);
  const unsigned int k20 = pack_cs(pB2[0]),  k21 = pack_cs(pB2[8]),
                     k22 = pack_cs(pB2[16]), k23 = pack_cs(pB2[24]);
  // Group C (stages 6-8): base 256w+l, stride 64.
  const float* pC0 = ang + 6 * 2048 + 256 * w + l;
  const float* pC1 = pC0 + 2048;
  const float* pC2 = pC1 + 2048;
  const unsigned int k24 = pack_cs(pC0[0]),   k25 = pack_cs(pC0[64]),
                     k26 = pack_cs(pC0[128]), k27 = pack_cs(pC0[192]);
  const unsigned int k28 = pack_cs(pC1[0]),   k29 = pack_cs(pC1[64]),
                     k30 = pack_cs(pC1[128]), k31 = pack_cs(pC1[192]);
  const unsigned int k32 = pack_cs(pC2[0]),   k33 = pack_cs(pC2[64]),
                     k34 = pack_cs(pC2[128]), k35 = pack_cs(pC2[192]);
  // Group D (stages 9-11): base t, stride 512.
  const float* pD0 = ang + 9 * 2048 + t;
  const float* pD1 = pD0 + 2048;
  const float* pD2 = pD1 + 2048;
  const unsigned int k36 = pack_cs(pD0[0]),    k37 = pack_cs(pD0[512]),
                     k38 = pack_cs(pD0[1024]), k39 = pack_cs(pD0[1536]);
  const unsigned int k40 = pack_cs(pD1[0]),    k41 = pack_cs(pD1[512]),
                     k42 = pack_cs(pD1[1024]), k43 = pack_cs(pD1[1536]);
  const unsigned int k44 = pack_cs(pD2[0]),    k45 = pack_cs(pD2[512]),
                     k46 = pack_cs(pD2[1024]), k47 = pack_cs(pD2[1536]);

  // ---------- LDS addresses (float indices), all scalar ----------
  // sw1 (im1, im2): 4-float chunk c stored at chunk c ^ ((c>>4)&7);
  // verified conflict-free (<=2 lanes/bank) for every access set.
  const int x  = (q >> 1) & 3;
  const int rr = r ^ ((q & 1) << 2);
  const int a0 = ((2 * t) ^ (q & 7)) << 2;      // sw1(elem 8t)   A-write f4 #0
  const int a1 = ((2 * t + 1) ^ (q & 7)) << 2;  // sw1(elem 8t+4) A-write f4 #1
  const int vB0 = 64 * q + rr + 8 * (0 ^ x);    // im1 B-read sw1(64q+r+8k); +32 -> k+4
  const int vB1 = 64 * q + rr + 8 * (1 ^ x);
  const int vB2 = 64 * q + rr + 8 * (2 ^ x);
  const int vB3 = 64 * q + rr + 8 * (3 ^ x);
  const int uB0 = vB0 + 4096, uB1 = vB1 + 4096; // im2 B-write (same swizzle)
  const int uB2 = vB2 + 4096, uB3 = vB3 + 4096;
  const int vC0 = 4096 + 512 * w + 64 * 0 + (l ^ (0 << 2));  // im2 C-read
  const int vC1 = 4096 + 512 * w + 64 * 1 + (l ^ (1 << 2));
  const int vC2 = 4096 + 512 * w + 64 * 2 + (l ^ (2 << 2));
  const int vC3 = 4096 + 512 * w + 64 * 3 + (l ^ (3 << 2));
  const int vC4 = 4096 + 512 * w + 64 * 4 + (l ^ (4 << 2));
  const int vC5 = 4096 + 512 * w + 64 * 5 + (l ^ (5 << 2));
  const int vC6 = 4096 + 512 * w + 64 * 6 + (l ^ (6 << 2));
  const int vC7 = 4096 + 512 * w + 64 * 7 + (l ^ (7 << 2));
  const int vCw = 8192 + 512 * w + l;           // im3 C-write, natural
  const int vD  = 8192 + t;                     // im3 D-read,  natural

  // ---------- row loop ----------
  const long long row0 = (long long)blockIdx.x * NROWS;
  const float* xbase = xin + row0 * NCOL + 8 * t;
  floatx4 rawA = __builtin_nontemporal_load((const floatx4*)xbase);
  floatx4 rawB = __builtin_nontemporal_load((const floatx4*)(xbase + 4));

  for (int rI = 0; rI < NROWS; ++rI) {
    float z0 = rawA.x, z1 = rawA.y, z2 = rawA.z, z3 = rawA.w;
    float z4 = rawB.x, z5 = rawB.y, z6 = rawB.z, z7 = rawB.w;
    if (rI + 1 < NROWS) {                       // prefetch next row (nontemporal)
      const float* nbase = xbase + (long long)(rI + 1) * NCOL;
      rawA = __builtin_nontemporal_load((const floatx4*)nbase);
      rawB = __builtin_nontemporal_load((const floatx4*)(nbase + 4));
    }

    GROUP3(k0, k1, k2, k3, k4, k5, k6, k7, k8, k9, k10, k11);   // stages 0-2

    floatx4 w0; w0.x = z0; w0.y = z1; w0.z = z2; w0.w = z3;     // A-write im1
    floatx4 w1; w1.x = z4; w1.y = z5; w1.z = z6; w1.w = z7;
    *(floatx4*)(lds + a0) = w0;
    *(floatx4*)(lds + a1) = w1;
    __syncthreads();

    z0 = lds[vB0]; z4 = lds[vB0 + 32];                          // B-read im1
    z1 = lds[vB1]; z5 = lds[vB1 + 32];
    z2 = lds[vB2]; z6 = lds[vB2 + 32];
    z3 = lds[vB3]; z7 = lds[vB3 + 32];
    GROUP3(k12, k13, k14, k15, k16, k17, k18, k19, k20, k21, k22, k23); // 3-5
    lds[uB0] = z0; lds[uB0 + 32] = z4;                          // B-write im2
    lds[uB1] = z1; lds[uB1 + 32] = z5;
    lds[uB2] = z2; lds[uB2 + 32] = z6;
    lds[uB3] = z3; lds[uB3 + 32] = z7;
    __syncthreads();

    z0 = lds[vC0]; z1 = lds[vC1]; z2 = lds[vC2]; z3 = lds[vC3]; // C-read im2
    z4 = lds[vC4]; z5 = lds[vC5]; z6 = lds[vC6]; z7 = lds[vC7];
    GROUP3(k24, k25, k26, k27, k28, k29, k30, k31, k32, k33, k34, k35); // 6-8
    lds[vCw + 64 * 0] = z0; lds[vCw + 64 * 1] = z1;             // C-write im3
    lds[vCw + 64 * 2] = z2; lds[vCw + 64 * 3] = z3;
    lds[vCw + 64 * 4] = z4; lds[vCw + 64 * 5] = z5;
    lds[vCw + 64 * 6] = z6; lds[vCw + 64 * 7] = z7;
    __syncthreads();

    z0 = lds[vD + 512 * 0]; z1 = lds[vD + 512 * 1];             // D-read im3
    z2 = lds[vD + 512 * 2]; z3 = lds[vD + 512 * 3];
    z4 = lds[vD + 512 * 4]; z5 = lds[vD + 512 * 5];
    z6 = lds[vD + 512 * 6]; z7 = lds[vD + 512 * 7];
    GROUP3(k36, k37, k38, k39, k40, k41, k42, k43, k44, k45, k46, k47); // 9-11

    float* orow = xout + (row0 + rI) * NCOL;                    // coalesced out
    __builtin_nontemporal_store(z0, orow + t + 512 * 0);
    __builtin_nontemporal_store(z1, orow + t + 512 * 1);
    __builtin_nontemporal_store(z2, orow + t + 512 * 2);
    __builtin_nontemporal_store(z3, orow + t + 512 * 3);
    __builtin_nontemporal_store(z4, orow + t + 512 * 4);
    __builtin_nontemporal_store(z5, orow + t + 512 * 5);
    __builtin_nontemporal_store(z6, orow + t + 512 * 6);
    __builtin_nontemporal_store(z7, orow + t + 512 * 7);
    // No extra barrier: row rI+1's im1 writes are ordered after row rI's
    // barrier #2 (im1 reads done); im2 writes after barrier #3; im3 writes
    // after rI+1's barrier #2 which is > all of rI's im3 reads.
  }
}

extern "C" void kernel_launch(void* const* d_in, const int* in_sizes, int n_in,
                              void* d_out, int out_size, void* d_ws, size_t ws_size,
                              hipStream_t stream) {
  const float* x   = (const float*)d_in[0];   // fp32 [4096][4096]
  const float* ang = (const float*)d_in[1];   // fp32 [12][2048]
  float* out = (float*)d_out;                 // fp32 [4096][4096]
  butterfly12_kernel<<<dim3(4096 / NROWS), dim3(BLOCK), 0, stream>>>(x, ang, out);
}